// Round 2
// baseline (247.589 us; speedup 1.0000x reference)
//
#include <hip/hip_runtime.h>

typedef __bf16 bf16x8 __attribute__((ext_vector_type(8)));
typedef __bf16 bf16x4 __attribute__((ext_vector_type(4)));
typedef float f32x4 __attribute__((ext_vector_type(4)));
typedef unsigned short u16;
typedef unsigned short u16x4 __attribute__((ext_vector_type(4)));
typedef unsigned int u32;

__device__ __forceinline__ u16 f2bu(float f) {
  __bf16 h = (__bf16)f;
  return __builtin_bit_cast(u16, h);
}

// async global->LDS, 16B/lane. LDS dest = wave-uniform base + lane*16.
__device__ __forceinline__ void gld16(const u16* g, const __bf16* lds) {
  __builtin_amdgcn_global_load_lds(
      (const __attribute__((address_space(1))) u32*)(uintptr_t)g,
      (__attribute__((address_space(3))) u32*)(u32)(uintptr_t)lds, 16, 0, 0);
}

// ---------------- transpose tile helper: out_bf16[C][R] tile from in_f32[R][C] -------
__device__ __forceinline__ void tr_tile(const float* __restrict__ in, u16* __restrict__ out,
                                        int R, int C, int bx, int by, int tid) {
  __shared__ u16 t[64][65];
  int tx = tid & 63, ty = tid >> 6;
  int r0 = by * 64, c0 = bx * 64;
  for (int i = 0; i < 16; ++i)
    t[ty + i * 4][tx] = f2bu(in[(size_t)(r0 + ty + i * 4) * C + c0 + tx]);
  __syncthreads();
  for (int i = 0; i < 16; ++i)
    out[(size_t)(c0 + ty + i * 4) * R + r0 + tx] = t[tx][ty + i * 4];
}

// ---------------- fused prep: tr(Wqkv) [0,768) | tr(Wout) [768,1024) | cvt(x) [1024,3072)
__global__ __launch_bounds__(256) void prep(const float* __restrict__ Wqkv,
                                            u16* __restrict__ Wqkv_t,
                                            const float* __restrict__ Wout,
                                            u16* __restrict__ Wout_t,
                                            const float* __restrict__ x,
                                            u16* __restrict__ xb) {
  int id = blockIdx.x, tid = threadIdx.x;
  if (id < 768) {
    tr_tile(Wqkv, Wqkv_t, 1024, 3072, id % 48, id / 48, tid);
  } else if (id < 1024) {
    int id2 = id - 768;
    tr_tile(Wout, Wout_t, 1024, 1024, id2 % 16, id2 / 16, tid);
  } else {
    size_t i = ((size_t)(id - 1024) * 256 + tid) * 8;
    f32x4 a0 = *(const f32x4*)(x + i);
    f32x4 a1 = *(const f32x4*)(x + i + 4);
    bf16x8 v;
    for (int j = 0; j < 4; ++j) { v[j] = (__bf16)a0[j]; v[j + 4] = (__bf16)a1[j]; }
    *(bf16x8*)(xb + i) = v;
  }
}

// ---------------- GEMM: dbuf K-loop, ONE barrier per 32-k step, XCD-swizzled --------
// MODE 0: C f32 -> O0.  MODE 1: qkv scatter -> Q(O0) K(O1) [b,h,s,d]; V -> O2
// TRANSPOSED [b,h,d,s] (replaces the old transpose_v kernel: acc r-quad = 4
// consecutive s at fixed d -> one 8B store).
template <int MODE, int TM, int TN, int MT, int NT, int XM, int XN>
__global__ __launch_bounds__(256) void gemm_bt(const u16* __restrict__ A,
                                               const u16* __restrict__ Bt,
                                               const float* __restrict__ bias,
                                               void* __restrict__ O0v,
                                               u16* __restrict__ O1,
                                               u16* __restrict__ O2,
                                               int M, int N, int K) {
  constexpr int NI = TM / 32;
  constexpr int NJ = TN / 32;
  constexpr int AE = TM * 32;
  constexpr int BE = TN * 32;
  __shared__ __bf16 smem[2 * (AE + BE)];

  int tid = threadIdx.x;
  int w = tid >> 6, lane = tid & 63, quad = lane >> 4, l16 = lane & 15;
  int wr = w >> 1, wc = w & 1;

  // XCD swizzle: xcd = id%8 owns tiles [mg*XM, mg*XM+XM) x [ng*XN, ng*XN+XN)
  int id = blockIdx.x;
  int xcd = id & 7, s0i = id >> 3;
  int mg = xcd % (MT / XM), ng = xcd / (MT / XM);
  int sm = s0i % XM, sn = s0i / XM;
  int m0 = (mg * XM + sm) * TM, n0 = (ng * XN + sn) * TN;

  int srow = w * 16 + (lane >> 2);
  int sch = (lane & 3) ^ ((lane >> 3) & 3);
  const u16* Ag = A + (size_t)(m0 + srow) * K + sch * 8;
  const u16* Bg = Bt + (size_t)(n0 + srow) * K + sch * 8;

  int swl = (quad ^ ((l16 >> 1) & 3)) << 3;

  f32x4 acc[NI][NJ] = {};

#define GLD_STEP(c, kk)                                                          \
  {                                                                              \
    for (int p = 0; p < TM / 64; ++p)                                            \
      gld16(Ag + (size_t)p * 64 * K + (kk), smem + (c) * (AE + BE) + w * 512 + p * 2048); \
    for (int p = 0; p < TN / 64; ++p)                                            \
      gld16(Bg + (size_t)p * 64 * K + (kk), smem + (c) * (AE + BE) + AE + w * 512 + p * 2048); \
  }

  GLD_STEP(0, 0);
  int NS = K / 32;
  for (int s = 0; s < NS; ++s) {
    int cur = s & 1;
    __syncthreads();  // drains step-s loads (issued one compute-phase ago)
    if (s + 1 < NS) GLD_STEP(1 - cur, (s + 1) * 32);
    const __bf16* Asub = smem + cur * (AE + BE);
    const __bf16* Bsub = Asub + AE;
    bf16x8 af[NI], bfr[NJ];
    for (int i = 0; i < NI; ++i)
      af[i] = *(const bf16x8*)(Asub + (wr * (TM / 2) + i * 16 + l16) * 32 + swl);
    for (int j = 0; j < NJ; ++j)
      bfr[j] = *(const bf16x8*)(Bsub + (wc * (TN / 2) + j * 16 + l16) * 32 + swl);
    for (int i = 0; i < NI; ++i)
      for (int j = 0; j < NJ; ++j)
        acc[i][j] = __builtin_amdgcn_mfma_f32_16x16x32_bf16(af[i], bfr[j], acc[i][j], 0, 0, 0);
  }
#undef GLD_STEP

  if (MODE == 0) {
    float* O0 = (float*)O0v;
    for (int j = 0; j < NJ; ++j) {
      int n = n0 + wc * (TN / 2) + j * 16 + l16;
      float bv = bias[n];
      for (int i = 0; i < NI; ++i) {
        int mb = m0 + wr * (TM / 2) + i * 16 + quad * 4;
        for (int r = 0; r < 4; ++r)
          O0[(size_t)(mb + r) * N + n] = acc[i][j][r] + bv;
      }
    }
  } else {
    u16* O0 = (u16*)O0v;
    for (int j = 0; j < NJ; ++j) {
      int n = n0 + wc * (TN / 2) + j * 16 + l16;
      int which = n >> 10, rem = n & 1023, h = rem >> 6, d = rem & 63;
      float bv = bias[n];
      for (int i = 0; i < NI; ++i) {
        int m = m0 + wr * (TM / 2) + i * 16 + quad * 4;
        int b = m >> 11, s = m & 2047;
        if (which == 2) {
          // V transposed: [b,h,d,s]; r-quad = 4 consecutive s (m) -> 8B store
          u16x4 val;
          for (int r = 0; r < 4; ++r) val[r] = f2bu(acc[i][j][r] + bv);
          *(u16x4*)(O2 + (((size_t)(b * 16 + h)) * 64 + d) * 2048 + s) = val;
        } else {
          u16* Od = which ? O1 : O0;
          for (int r = 0; r < 4; ++r)
            Od[(((size_t)(b * 16 + h)) * 2048 + (s + r)) * 64 + d] = f2bu(acc[i][j][r] + bv);
        }
      }
    }
  }
}

// ---------------- flash attention v3: NO K/V LDS staging, NO barriers --------------
// R1 counters: no pipe >42% (VALU 40, LDS ~42, MFMA 26), FETCH 21MB -> K/V is
// L2/L3-resident. Per m169 lesson, drop LDS staging of cache-fit data: read K/V
// fragments DIRECT from global (L2), Ps stays in LDS (wave-local, no barrier
// needed). Waves free-run; K prefetched one 64-tile ahead in regs; V issued at
// iter top and hidden under QK+exp. Grid 1-D 512, swizzled so each XCD's 4
// heads (2MB K+V) fit its private 4MB L2.
__global__ __launch_bounds__(256, 2) void flash_attn(const u16* __restrict__ Q,
                                                     const u16* __restrict__ K,
                                                     const u16* __restrict__ Vt,
                                                     u16* __restrict__ AO) {
  constexpr int S = 2048;
  constexpr int NITER = S / 64;
  __shared__ __bf16 Ps[4][32 * 64];

  int id = blockIdx.x;
  int xcd = id & 7, kk = id >> 3;
  int bh = xcd * 4 + (kk & 3);
  int qbase = (kk >> 2) * 128;

  int tid = threadIdx.x, w = tid >> 6, lane = tid & 63, quad = lane >> 4, l16 = lane & 15;

  const u16* Qh = Q + (size_t)bh * S * 64;
  const u16* Kh = K + (size_t)bh * S * 64;
  const u16* Vh = Vt + (size_t)bh * 64 * S;  // Vt[d][s]

  // two q-row groups per wave: A = w*32 + l16, B = A + 16
  int qrowA = qbase + w * 32 + l16;
  int qrowB = qrowA + 16;
  bf16x8 qf0a = *(const bf16x8*)(Qh + (size_t)qrowA * 64 + quad * 8);
  bf16x8 qf1a = *(const bf16x8*)(Qh + (size_t)qrowA * 64 + 32 + quad * 8);
  bf16x8 qf0b = *(const bf16x8*)(Qh + (size_t)qrowB * 64 + quad * 8);
  bf16x8 qf1b = *(const bf16x8*)(Qh + (size_t)qrowB * 64 + 32 + quad * 8);

  // per-lane fragment base pointers (no swizzle needed from global)
  const u16* Kp = Kh + (size_t)l16 * 64 + quad * 8;  // + (tb + nt*16)*64 + {0,32}
  const u16* Vp = Vh + (size_t)l16 * S + quad * 8;   // + dt*16*S + tb + {0,32}

  constexpr float C1 = 0.125f * 1.44269504f;
  constexpr float C0 = -12.0f * 1.44269504f;

  float lA = 0.f, lB = 0.f;
  f32x4 oA[4] = {};
  f32x4 oB[4] = {};
  int xr = l16 & 7;
  int pw_baseA = l16 * 64 + (quad & 1) * 4;
  int pw_baseB = (l16 + 16) * 64 + (quad & 1) * 4;  // row 16+l16 has same xr
  int pw_blk = quad >> 1;

  bf16x8 kf[8];
#pragma unroll
  for (int nt = 0; nt < 4; ++nt) {
    kf[2 * nt]     = *(const bf16x8*)(Kp + (size_t)(nt * 16) * 64);
    kf[2 * nt + 1] = *(const bf16x8*)(Kp + (size_t)(nt * 16) * 64 + 32);
  }

#pragma unroll 2
  for (int it = 0; it < NITER; ++it) {
    int tb = it * 64;
    // V for this tile: issued now, consumed after QK+exp (~600cy slack)
    bf16x8 vv[8];
#pragma unroll
    for (int dt = 0; dt < 4; ++dt) {
      vv[2 * dt]     = *(const bf16x8*)(Vp + (size_t)(dt * 16) * S + tb);
      vv[2 * dt + 1] = *(const bf16x8*)(Vp + (size_t)(dt * 16) * S + tb + 32);
    }
    // K prefetch for next tile (clamped at last iter to avoid OOB; harmless re-read)
    int nb = (it + 1 < NITER) ? tb + 64 : tb;
    bf16x8 kn[8];
#pragma unroll
    for (int nt = 0; nt < 4; ++nt) {
      kn[2 * nt]     = *(const bf16x8*)(Kp + (size_t)(nb + nt * 16) * 64);
      kn[2 * nt + 1] = *(const bf16x8*)(Kp + (size_t)(nb + nt * 16) * 64 + 32);
    }

#pragma unroll
    for (int nt = 0; nt < 4; ++nt) {
      f32x4 ca = {0.f, 0.f, 0.f, 0.f};
      f32x4 cb = {0.f, 0.f, 0.f, 0.f};
      __builtin_amdgcn_s_setprio(1);
      ca = __builtin_amdgcn_mfma_f32_16x16x32_bf16(kf[2 * nt], qf0a, ca, 0, 0, 0);
      cb = __builtin_amdgcn_mfma_f32_16x16x32_bf16(kf[2 * nt], qf0b, cb, 0, 0, 0);
      ca = __builtin_amdgcn_mfma_f32_16x16x32_bf16(kf[2 * nt + 1], qf1a, ca, 0, 0, 0);
      cb = __builtin_amdgcn_mfma_f32_16x16x32_bf16(kf[2 * nt + 1], qf1b, cb, 0, 0, 0);
      __builtin_amdgcn_s_setprio(0);
      bf16x4 pka, pkb;
#pragma unroll
      for (int r = 0; r < 4; ++r) {
        float pa = __builtin_amdgcn_exp2f(fmaf(ca[r], C1, C0));
        float pb = __builtin_amdgcn_exp2f(fmaf(cb[r], C1, C0));
        lA += pa;
        lB += pb;
        pka[r] = (__bf16)pa;
        pkb[r] = (__bf16)pb;
      }
      int pc = (((nt * 2 + pw_blk) ^ xr) << 3);
      *(bf16x4*)(&Ps[w][pw_baseA + pc]) = pka;
      *(bf16x4*)(&Ps[w][pw_baseB + pc]) = pkb;
    }

    bf16x8 pf0a = *(const bf16x8*)(&Ps[w][l16 * 64 + ((quad ^ xr) << 3)]);
    bf16x8 pf1a = *(const bf16x8*)(&Ps[w][l16 * 64 + (((quad + 4) ^ xr) << 3)]);
    bf16x8 pf0b = *(const bf16x8*)(&Ps[w][(l16 + 16) * 64 + ((quad ^ xr) << 3)]);
    bf16x8 pf1b = *(const bf16x8*)(&Ps[w][(l16 + 16) * 64 + (((quad + 4) ^ xr) << 3)]);
#pragma unroll
    for (int dt = 0; dt < 4; ++dt) {
      __builtin_amdgcn_s_setprio(1);
      oA[dt] = __builtin_amdgcn_mfma_f32_16x16x32_bf16(pf0a, vv[2 * dt], oA[dt], 0, 0, 0);
      oB[dt] = __builtin_amdgcn_mfma_f32_16x16x32_bf16(pf0b, vv[2 * dt], oB[dt], 0, 0, 0);
      oA[dt] = __builtin_amdgcn_mfma_f32_16x16x32_bf16(pf1a, vv[2 * dt + 1], oA[dt], 0, 0, 0);
      oB[dt] = __builtin_amdgcn_mfma_f32_16x16x32_bf16(pf1b, vv[2 * dt + 1], oB[dt], 0, 0, 0);
      __builtin_amdgcn_s_setprio(0);
    }

#pragma unroll
    for (int z = 0; z < 8; ++z) kf[z] = kn[z];
  }

  lA += __shfl_xor(lA, 16);
  lA += __shfl_xor(lA, 32);
  lB += __shfl_xor(lB, 16);
  lB += __shfl_xor(lB, 32);
  float linvA[4], linvB[4];
  for (int r = 0; r < 4; ++r) {
    linvA[r] = 1.f / __shfl(lA, quad * 4 + r);
    linvB[r] = 1.f / __shfl(lB, quad * 4 + r);
  }

  int b = bh >> 4, h = bh & 15;
  for (int dt = 0; dt < 4; ++dt)
    for (int r = 0; r < 4; ++r) {
      int sA = qbase + w * 32 + quad * 4 + r;
      int sB = sA + 16;
      int d = dt * 16 + l16;
      AO[(((size_t)b * 2048 + sA) * 16 + h) * 64 + d] = f2bu(oA[dt][r] * linvA[r]);
      AO[(((size_t)b * 2048 + sB) * 16 + h) * 64 + d] = f2bu(oB[dt][r] * linvB[r]);
    }
}

// ---------------- launch ----------------
extern "C" void kernel_launch(void* const* d_in, const int* in_sizes, int n_in,
                              void* d_out, int out_size, void* d_ws, size_t ws_size,
                              hipStream_t stream) {
  const float* x    = (const float*)d_in[0];  // [4096,1024] f32
  const float* Wqkv = (const float*)d_in[1];  // [1024,3072] f32
  const float* bqkv = (const float*)d_in[2];  // [3072] f32
  const float* Wout = (const float*)d_in[3];  // [1024,1024] f32
  const float* bout = (const float*)d_in[4];  // [1024] f32
  float* out = (float*)d_out;                 // [4096,1024] f32

  u16* ws = (u16*)d_ws;
  size_t off = 0;
  u16* Wqkv_t = ws + off; off += (size_t)3072 * 1024;
  u16* Wout_t = ws + off; off += (size_t)1024 * 1024;
  u16* xb     = ws + off; off += (size_t)4096 * 1024;  // AO aliases xb (dead after gemm1)
  u16* Qb     = ws + off; off += (size_t)32 * 2048 * 64;
  u16* Kb     = ws + off; off += (size_t)32 * 2048 * 64;
  u16* Vtb    = ws + off; off += (size_t)32 * 2048 * 64;  // written TRANSPOSED by gemm1
  u16* AO     = xb;
  // total: ~42 MB

  prep<<<dim3(3072), 256, 0, stream>>>(Wqkv, Wqkv_t, Wout, Wout_t, x, xb);
  // gemm1: 32 m-tiles x 24 n-tiles (TM=TN=128); XCD region 8m x 12n (A 2MB + Bt 3MB / L2)
  gemm_bt<1, 128, 128, 32, 24, 8, 12><<<dim3(768), 256, 0, stream>>>(
      xb, Wqkv_t, bqkv, (void*)Qb, Kb, Vtb, 4096, 3072, 1024);
  // flash: 128 q-rows per block (32/wave), 1-D grid 512 XCD-swizzled
  flash_attn<<<dim3(512), 256, 0, stream>>>(Qb, Kb, Vtb, AO);
  // gemm2: 32 m-tiles x 16 n-tiles (TM=128, TN=64); XCD region 8m x 8n (A 2MB + Bt 1MB / L2)
  gemm_bt<0, 128, 64, 32, 16, 8, 8><<<dim3(512), 256, 0, stream>>>(
      AO, Wout_t, bout, (void*)out, nullptr, nullptr, 4096, 1024, 1024);
}

// Round 3
// 178.047 us; speedup vs baseline: 1.3906x; 1.3906x over previous
//
#include <hip/hip_runtime.h>

typedef __bf16 bf16x8 __attribute__((ext_vector_type(8)));
typedef __bf16 bf16x4 __attribute__((ext_vector_type(4)));
typedef float f32x4 __attribute__((ext_vector_type(4)));
typedef unsigned short u16;
typedef unsigned short u16x4 __attribute__((ext_vector_type(4)));
typedef unsigned int u32;

__device__ __forceinline__ u16 f2bu(float f) {
  __bf16 h = (__bf16)f;
  return __builtin_bit_cast(u16, h);
}

// async global->LDS, 16B/lane. LDS dest = wave-uniform base + lane*16.
__device__ __forceinline__ void gld16(const u16* g, const __bf16* lds) {
  __builtin_amdgcn_global_load_lds(
      (const __attribute__((address_space(1))) u32*)(uintptr_t)g,
      (__attribute__((address_space(3))) u32*)(u32)(uintptr_t)lds, 16, 0, 0);
}

// ---------------- transpose tile helper: out_bf16[C][R] tile from in_f32[R][C] -------
__device__ __forceinline__ void tr_tile(const float* __restrict__ in, u16* __restrict__ out,
                                        int R, int C, int bx, int by, int tid) {
  __shared__ u16 t[64][65];
  int tx = tid & 63, ty = tid >> 6;
  int r0 = by * 64, c0 = bx * 64;
  for (int i = 0; i < 16; ++i)
    t[ty + i * 4][tx] = f2bu(in[(size_t)(r0 + ty + i * 4) * C + c0 + tx]);
  __syncthreads();
  for (int i = 0; i < 16; ++i)
    out[(size_t)(c0 + ty + i * 4) * R + r0 + tx] = t[tx][ty + i * 4];
}

// ---------------- fused prep: tr(Wqkv) [0,768) | tr(Wout) [768,1024) | cvt(x) [1024,3072)
__global__ __launch_bounds__(256) void prep(const float* __restrict__ Wqkv,
                                            u16* __restrict__ Wqkv_t,
                                            const float* __restrict__ Wout,
                                            u16* __restrict__ Wout_t,
                                            const float* __restrict__ x,
                                            u16* __restrict__ xb) {
  int id = blockIdx.x, tid = threadIdx.x;
  if (id < 768) {
    tr_tile(Wqkv, Wqkv_t, 1024, 3072, id % 48, id / 48, tid);
  } else if (id < 1024) {
    int id2 = id - 768;
    tr_tile(Wout, Wout_t, 1024, 1024, id2 % 16, id2 / 16, tid);
  } else {
    size_t i = ((size_t)(id - 1024) * 256 + tid) * 8;
    f32x4 a0 = *(const f32x4*)(x + i);
    f32x4 a1 = *(const f32x4*)(x + i + 4);
    bf16x8 v;
    for (int j = 0; j < 4; ++j) { v[j] = (__bf16)a0[j]; v[j + 4] = (__bf16)a1[j]; }
    *(bf16x8*)(xb + i) = v;
  }
}

// ---------------- GEMM: dbuf K-loop, ONE barrier per 32-k step, XCD-swizzled --------
// MODE 0: C f32 -> O0.
// MODE 1: qkv scatter. Q(O0) scaled by 0.125*log2(e) (softmax scale folded in so
// flash does p=exp2(dot) directly), [b,h,s,d]. K(O1) [b,h,s,d]. V(O2) TRANSPOSED
// [b,h,d,s]: acc r-quad = 4 consecutive s at fixed d -> one 8B store (replaces
// the old transpose_v kernel).
template <int MODE, int TM, int TN, int MT, int NT, int XM, int XN>
__global__ __launch_bounds__(256) void gemm_bt(const u16* __restrict__ A,
                                               const u16* __restrict__ Bt,
                                               const float* __restrict__ bias,
                                               void* __restrict__ O0v,
                                               u16* __restrict__ O1,
                                               u16* __restrict__ O2,
                                               int M, int N, int K) {
  constexpr int NI = TM / 32;
  constexpr int NJ = TN / 32;
  constexpr int AE = TM * 32;
  constexpr int BE = TN * 32;
  __shared__ __bf16 smem[2 * (AE + BE)];

  int tid = threadIdx.x;
  int w = tid >> 6, lane = tid & 63, quad = lane >> 4, l16 = lane & 15;
  int wr = w >> 1, wc = w & 1;

  // XCD swizzle: xcd = id%8 owns tiles [mg*XM, mg*XM+XM) x [ng*XN, ng*XN+XN)
  int id = blockIdx.x;
  int xcd = id & 7, s0i = id >> 3;
  int mg = xcd % (MT / XM), ng = xcd / (MT / XM);
  int sm = s0i % XM, sn = s0i / XM;
  int m0 = (mg * XM + sm) * TM, n0 = (ng * XN + sn) * TN;

  int srow = w * 16 + (lane >> 2);
  int sch = (lane & 3) ^ ((lane >> 3) & 3);
  const u16* Ag = A + (size_t)(m0 + srow) * K + sch * 8;
  const u16* Bg = Bt + (size_t)(n0 + srow) * K + sch * 8;

  int swl = (quad ^ ((l16 >> 1) & 3)) << 3;

  f32x4 acc[NI][NJ] = {};

#define GLD_STEP(c, kk)                                                          \
  {                                                                              \
    for (int p = 0; p < TM / 64; ++p)                                            \
      gld16(Ag + (size_t)p * 64 * K + (kk), smem + (c) * (AE + BE) + w * 512 + p * 2048); \
    for (int p = 0; p < TN / 64; ++p)                                            \
      gld16(Bg + (size_t)p * 64 * K + (kk), smem + (c) * (AE + BE) + AE + w * 512 + p * 2048); \
  }

  GLD_STEP(0, 0);
  int NS = K / 32;
  for (int s = 0; s < NS; ++s) {
    int cur = s & 1;
    __syncthreads();  // drains step-s loads (issued one compute-phase ago)
    if (s + 1 < NS) GLD_STEP(1 - cur, (s + 1) * 32);
    const __bf16* Asub = smem + cur * (AE + BE);
    const __bf16* Bsub = Asub + AE;
    bf16x8 af[NI], bfr[NJ];
    for (int i = 0; i < NI; ++i)
      af[i] = *(const bf16x8*)(Asub + (wr * (TM / 2) + i * 16 + l16) * 32 + swl);
    for (int j = 0; j < NJ; ++j)
      bfr[j] = *(const bf16x8*)(Bsub + (wc * (TN / 2) + j * 16 + l16) * 32 + swl);
    for (int i = 0; i < NI; ++i)
      for (int j = 0; j < NJ; ++j)
        acc[i][j] = __builtin_amdgcn_mfma_f32_16x16x32_bf16(af[i], bfr[j], acc[i][j], 0, 0, 0);
  }
#undef GLD_STEP

  if (MODE == 0) {
    float* O0 = (float*)O0v;
    for (int j = 0; j < NJ; ++j) {
      int n = n0 + wc * (TN / 2) + j * 16 + l16;
      float bv = bias[n];
      for (int i = 0; i < NI; ++i) {
        int mb = m0 + wr * (TM / 2) + i * 16 + quad * 4;
        for (int r = 0; r < 4; ++r)
          O0[(size_t)(mb + r) * N + n] = acc[i][j][r] + bv;
      }
    }
  } else {
    u16* O0 = (u16*)O0v;
    constexpr float QSC = 0.125f * 1.44269504f;  // softmax scale * log2(e) folded into Q
    for (int j = 0; j < NJ; ++j) {
      int n = n0 + wc * (TN / 2) + j * 16 + l16;
      int which = n >> 10, rem = n & 1023, h = rem >> 6, d = rem & 63;
      float bv = bias[n];
      for (int i = 0; i < NI; ++i) {
        int m = m0 + wr * (TM / 2) + i * 16 + quad * 4;
        int b = m >> 11, s = m & 2047;
        if (which == 2) {
          // V transposed: [b,h,d,s]; r-quad = 4 consecutive s (m) -> 8B store
          u16x4 val;
          for (int r = 0; r < 4; ++r) val[r] = f2bu(acc[i][j][r] + bv);
          *(u16x4*)(O2 + (((size_t)(b * 16 + h)) * 64 + d) * 2048 + s) = val;
        } else {
          u16* Od = which ? O1 : O0;
          float sc = which ? 1.f : QSC;
          for (int r = 0; r < 4; ++r)
            Od[(((size_t)(b * 16 + h)) * 2048 + (s + r)) * 64 + d] = f2bu((acc[i][j][r] + bv) * sc);
        }
      }
    }
  }
}

// ---------------- flash attention (R1 55.4us structure + VALU-chain cuts) -----------
// grid (B*H=32, S/128=16), 256 threads (4 waves); wave owns 32 q-rows (2 groups).
// R3 deltas vs R1: (1) Q pre-scaled in gemm1 -> p = exp2(dot) directly, no fmaf/C0;
// (2) l computed via MFMA with ones-B fragment (removes the serial 32-deep add
// chain per iter AND the end shuffle-reduce: l-fragment C-layout row quad*4+r
// matches o's row exactly); (3) transposed V produced by gemm1.
__global__ __launch_bounds__(256, 2) void flash_attn(const u16* __restrict__ Q,
                                                     const u16* __restrict__ K,
                                                     const u16* __restrict__ Vt,
                                                     u16* __restrict__ AO) {
  constexpr int S = 2048;
  __shared__ __bf16 Ks[2][64 * 64];
  __shared__ __bf16 Vs[2][64 * 64];
  __shared__ __bf16 Ps[4][32 * 64];

  int bh = blockIdx.x, qbase = blockIdx.y * 128;
  int tid = threadIdx.x, w = tid >> 6, lane = tid & 63, quad = lane >> 4, l16 = lane & 15;

  const u16* Qh = Q + (size_t)bh * S * 64;
  const u16* Kh = K + (size_t)bh * S * 64;
  const u16* Vh = Vt + (size_t)bh * 64 * S;  // Vt[d][s]

  // two q-row groups per wave: A = w*32 + l16, B = A + 16
  int qrowA = qbase + w * 32 + l16;
  int qrowB = qrowA + 16;
  bf16x8 qf0a = *(const bf16x8*)(Qh + (size_t)qrowA * 64 + quad * 8);
  bf16x8 qf1a = *(const bf16x8*)(Qh + (size_t)qrowA * 64 + 32 + quad * 8);
  bf16x8 qf0b = *(const bf16x8*)(Qh + (size_t)qrowB * 64 + quad * 8);
  bf16x8 qf1b = *(const bf16x8*)(Qh + (size_t)qrowB * 64 + 32 + quad * 8);

  bf16x8 vone;
#pragma unroll
  for (int j = 0; j < 8; ++j) vone[j] = (__bf16)1.0f;

  int r0s = tid >> 3, b0s = tid & 7;
  int r1s = r0s + 32;
  int ko0 = r0s * 64 + ((b0s ^ (r0s & 7)) << 3);
  int ko1 = r1s * 64 + ((b0s ^ (r1s & 7)) << 3);

  bf16x8 kr0, kr1, vr0, vr1;
#define LOAD_TILE(tb)                                                   \
  {                                                                     \
    kr0 = *(const bf16x8*)(Kh + (size_t)((tb) + r0s) * 64 + b0s * 8);   \
    kr1 = *(const bf16x8*)(Kh + (size_t)((tb) + r1s) * 64 + b0s * 8);   \
    vr0 = *(const bf16x8*)(Vh + (size_t)r0s * S + (tb) + b0s * 8);      \
    vr1 = *(const bf16x8*)(Vh + (size_t)r1s * S + (tb) + b0s * 8);      \
  }
#define STORE_TILE(c)                                                   \
  {                                                                     \
    *(bf16x8*)(&Ks[c][ko0]) = kr0;                                      \
    *(bf16x8*)(&Ks[c][ko1]) = kr1;                                      \
    *(bf16x8*)(&Vs[c][ko0]) = vr0;                                      \
    *(bf16x8*)(&Vs[c][ko1]) = vr1;                                      \
  }

  LOAD_TILE(0);
  STORE_TILE(0);
  LOAD_TILE(64);
  __syncthreads();

  f32x4 oA[4] = {};
  f32x4 oB[4] = {};
  f32x4 lfA = {};
  f32x4 lfB = {};
  int xr = l16 & 7;
  int pw_baseA = l16 * 64 + (quad & 1) * 4;
  int pw_baseB = (l16 + 16) * 64 + (quad & 1) * 4;  // row 16+l16 has same xr
  int pw_blk = quad >> 1;

  for (int it = 0; it < S / 64; ++it) {
    int c = it & 1;
    if (it + 1 < S / 64) STORE_TILE(1 - c);
    if (it + 2 < S / 64) LOAD_TILE((it + 2) * 64);

    for (int nt = 0; nt < 4; ++nt) {
      const __bf16* kb = &Ks[c][(nt * 16 + l16) * 64];
      bf16x8 kf0 = *(const bf16x8*)(kb + ((quad ^ xr) << 3));
      bf16x8 kf1 = *(const bf16x8*)(kb + (((quad + 4) ^ xr) << 3));
      f32x4 ca = {0.f, 0.f, 0.f, 0.f};
      f32x4 cb = {0.f, 0.f, 0.f, 0.f};
      ca = __builtin_amdgcn_mfma_f32_16x16x32_bf16(kf0, qf0a, ca, 0, 0, 0);
      cb = __builtin_amdgcn_mfma_f32_16x16x32_bf16(kf0, qf0b, cb, 0, 0, 0);
      ca = __builtin_amdgcn_mfma_f32_16x16x32_bf16(kf1, qf1a, ca, 0, 0, 0);
      cb = __builtin_amdgcn_mfma_f32_16x16x32_bf16(kf1, qf1b, cb, 0, 0, 0);
      bf16x4 pka, pkb;
#pragma unroll
      for (int r = 0; r < 4; ++r) {
        pka[r] = (__bf16)__builtin_amdgcn_exp2f(ca[r]);
        pkb[r] = (__bf16)__builtin_amdgcn_exp2f(cb[r]);
      }
      int pc = (((nt * 2 + pw_blk) ^ xr) << 3);
      *(bf16x4*)(&Ps[w][pw_baseA + pc]) = pka;
      *(bf16x4*)(&Ps[w][pw_baseB + pc]) = pkb;
    }

    bf16x8 pf0a = *(const bf16x8*)(&Ps[w][l16 * 64 + ((quad ^ xr) << 3)]);
    bf16x8 pf1a = *(const bf16x8*)(&Ps[w][l16 * 64 + (((quad + 4) ^ xr) << 3)]);
    bf16x8 pf0b = *(const bf16x8*)(&Ps[w][(l16 + 16) * 64 + ((quad ^ xr) << 3)]);
    bf16x8 pf1b = *(const bf16x8*)(&Ps[w][(l16 + 16) * 64 + (((quad + 4) ^ xr) << 3)]);

    // l = row-sums of P via matrix pipe (B = ones); C-layout row matches o's row.
    lfA = __builtin_amdgcn_mfma_f32_16x16x32_bf16(pf0a, vone, lfA, 0, 0, 0);
    lfA = __builtin_amdgcn_mfma_f32_16x16x32_bf16(pf1a, vone, lfA, 0, 0, 0);
    lfB = __builtin_amdgcn_mfma_f32_16x16x32_bf16(pf0b, vone, lfB, 0, 0, 0);
    lfB = __builtin_amdgcn_mfma_f32_16x16x32_bf16(pf1b, vone, lfB, 0, 0, 0);

    for (int dt = 0; dt < 4; ++dt) {
      const __bf16* vb = &Vs[c][(dt * 16 + l16) * 64];
      bf16x8 v0 = *(const bf16x8*)(vb + ((quad ^ xr) << 3));
      bf16x8 v1 = *(const bf16x8*)(vb + (((quad + 4) ^ xr) << 3));
      oA[dt] = __builtin_amdgcn_mfma_f32_16x16x32_bf16(pf0a, v0, oA[dt], 0, 0, 0);
      oB[dt] = __builtin_amdgcn_mfma_f32_16x16x32_bf16(pf0b, v0, oB[dt], 0, 0, 0);
      oA[dt] = __builtin_amdgcn_mfma_f32_16x16x32_bf16(pf1a, v1, oA[dt], 0, 0, 0);
      oB[dt] = __builtin_amdgcn_mfma_f32_16x16x32_bf16(pf1b, v1, oB[dt], 0, 0, 0);
    }
    __syncthreads();
  }
#undef LOAD_TILE
#undef STORE_TILE

  float linvA[4], linvB[4];
#pragma unroll
  for (int r = 0; r < 4; ++r) {
    linvA[r] = 1.f / lfA[r];
    linvB[r] = 1.f / lfB[r];
  }

  int b = bh >> 4, h = bh & 15;
  for (int dt = 0; dt < 4; ++dt)
    for (int r = 0; r < 4; ++r) {
      int sA = qbase + w * 32 + quad * 4 + r;
      int sB = sA + 16;
      int d = dt * 16 + l16;
      AO[(((size_t)b * 2048 + sA) * 16 + h) * 64 + d] = f2bu(oA[dt][r] * linvA[r]);
      AO[(((size_t)b * 2048 + sB) * 16 + h) * 64 + d] = f2bu(oB[dt][r] * linvB[r]);
    }
}

// ---------------- launch ----------------
extern "C" void kernel_launch(void* const* d_in, const int* in_sizes, int n_in,
                              void* d_out, int out_size, void* d_ws, size_t ws_size,
                              hipStream_t stream) {
  const float* x    = (const float*)d_in[0];  // [4096,1024] f32
  const float* Wqkv = (const float*)d_in[1];  // [1024,3072] f32
  const float* bqkv = (const float*)d_in[2];  // [3072] f32
  const float* Wout = (const float*)d_in[3];  // [1024,1024] f32
  const float* bout = (const float*)d_in[4];  // [1024] f32
  float* out = (float*)d_out;                 // [4096,1024] f32

  u16* ws = (u16*)d_ws;
  size_t off = 0;
  u16* Wqkv_t = ws + off; off += (size_t)3072 * 1024;
  u16* Wout_t = ws + off; off += (size_t)1024 * 1024;
  u16* xb     = ws + off; off += (size_t)4096 * 1024;  // AO aliases xb (dead after gemm1)
  u16* Qb     = ws + off; off += (size_t)32 * 2048 * 64;
  u16* Kb     = ws + off; off += (size_t)32 * 2048 * 64;
  u16* Vtb    = ws + off; off += (size_t)32 * 2048 * 64;  // written TRANSPOSED by gemm1
  u16* AO     = xb;
  // total: ~42 MB

  prep<<<dim3(3072), 256, 0, stream>>>(Wqkv, Wqkv_t, Wout, Wout_t, x, xb);
  // gemm1: 32 m-tiles x 24 n-tiles (TM=TN=128); XCD region 8m x 12n (A 2MB + Bt 3MB / L2)
  gemm_bt<1, 128, 128, 32, 24, 8, 12><<<dim3(768), 256, 0, stream>>>(
      xb, Wqkv_t, bqkv, (void*)Qb, Kb, Vtb, 4096, 3072, 1024);
  // flash: 128 q-rows per block (32/wave), grid (B*H, S/128); blockIdx.x fastest ->
  // all q-blocks of head bh land on XCD bh%8 (4 heads x 512KB K+V = 2MB per L2)
  flash_attn<<<dim3(32, 16), 256, 0, stream>>>(Qb, Kb, Vtb, AO);
  // gemm2: 32 m-tiles x 16 n-tiles (TM=128, TN=64); XCD region 8m x 8n (A 2MB + Bt 1MB / L2)
  gemm_bt<0, 128, 64, 32, 16, 8, 8><<<dim3(512), 256, 0, stream>>>(
      AO, Wout_t, bout, (void*)out, nullptr, nullptr, 4096, 1024, 1024);
}

// Round 4
// 173.659 us; speedup vs baseline: 1.4257x; 1.0253x over previous
//
#include <hip/hip_runtime.h>

typedef __bf16 bf16x8 __attribute__((ext_vector_type(8)));
typedef __bf16 bf16x4 __attribute__((ext_vector_type(4)));
typedef __bf16 bf16x2 __attribute__((ext_vector_type(2)));
typedef float f32x4 __attribute__((ext_vector_type(4)));
typedef unsigned short u16;
typedef unsigned short u16x4 __attribute__((ext_vector_type(4)));
typedef unsigned int u32;
typedef unsigned int u32x2 __attribute__((ext_vector_type(2)));
typedef unsigned int u32x4 __attribute__((ext_vector_type(4)));

__device__ __forceinline__ u16 f2bu(float f) {
  __bf16 h = (__bf16)f;
  return __builtin_bit_cast(u16, h);
}

// async global->LDS, 16B/lane. LDS dest = wave-uniform base + lane*16.
__device__ __forceinline__ void gld16(const u16* g, const __bf16* lds) {
  __builtin_amdgcn_global_load_lds(
      (const __attribute__((address_space(1))) u32*)(uintptr_t)g,
      (__attribute__((address_space(3))) u32*)(u32)(uintptr_t)lds, 16, 0, 0);
}

// ---------------- transpose tile helper: out_bf16[C][R] tile from in_f32[R][C] -------
__device__ __forceinline__ void tr_tile(const float* __restrict__ in, u16* __restrict__ out,
                                        int R, int C, int bx, int by, int tid) {
  __shared__ u16 t[64][65];
  int tx = tid & 63, ty = tid >> 6;
  int r0 = by * 64, c0 = bx * 64;
  for (int i = 0; i < 16; ++i)
    t[ty + i * 4][tx] = f2bu(in[(size_t)(r0 + ty + i * 4) * C + c0 + tx]);
  __syncthreads();
  for (int i = 0; i < 16; ++i)
    out[(size_t)(c0 + ty + i * 4) * R + r0 + tx] = t[tx][ty + i * 4];
}

// ---------------- fused prep: tr(Wqkv) [0,768) | tr(Wout) [768,1024) | cvt(x) [1024,3072)
__global__ __launch_bounds__(256) void prep(const float* __restrict__ Wqkv,
                                            u16* __restrict__ Wqkv_t,
                                            const float* __restrict__ Wout,
                                            u16* __restrict__ Wout_t,
                                            const float* __restrict__ x,
                                            u16* __restrict__ xb) {
  int id = blockIdx.x, tid = threadIdx.x;
  if (id < 768) {
    tr_tile(Wqkv, Wqkv_t, 1024, 3072, id % 48, id / 48, tid);
  } else if (id < 1024) {
    int id2 = id - 768;
    tr_tile(Wout, Wout_t, 1024, 1024, id2 % 16, id2 / 16, tid);
  } else {
    size_t i = ((size_t)(id - 1024) * 256 + tid) * 8;
    f32x4 a0 = *(const f32x4*)(x + i);
    f32x4 a1 = *(const f32x4*)(x + i + 4);
    bf16x8 v;
    for (int j = 0; j < 4; ++j) { v[j] = (__bf16)a0[j]; v[j + 4] = (__bf16)a1[j]; }
    *(bf16x8*)(xb + i) = v;
  }
}

// ---------------- GEMM: dbuf K-loop, ONE barrier per 32-k step, XCD-swizzled --------
// MODE 0: C f32 -> O0.
// MODE 1: qkv scatter. Q(O0) scaled by 0.125*log2(e) (softmax scale folded in so
// flash does p=exp2(dot) directly), [b,h,s,d]. K(O1) [b,h,s,d]. V(O2) TRANSPOSED
// [b,h,d,s]: acc r-quad = 4 consecutive s at fixed d -> one 8B store (replaces
// the old transpose_v kernel).
template <int MODE, int TM, int TN, int MT, int NT, int XM, int XN>
__global__ __launch_bounds__(256) void gemm_bt(const u16* __restrict__ A,
                                               const u16* __restrict__ Bt,
                                               const float* __restrict__ bias,
                                               void* __restrict__ O0v,
                                               u16* __restrict__ O1,
                                               u16* __restrict__ O2,
                                               int M, int N, int K) {
  constexpr int NI = TM / 32;
  constexpr int NJ = TN / 32;
  constexpr int AE = TM * 32;
  constexpr int BE = TN * 32;
  __shared__ __bf16 smem[2 * (AE + BE)];

  int tid = threadIdx.x;
  int w = tid >> 6, lane = tid & 63, quad = lane >> 4, l16 = lane & 15;
  int wr = w >> 1, wc = w & 1;

  // XCD swizzle: xcd = id%8 owns tiles [mg*XM, mg*XM+XM) x [ng*XN, ng*XN+XN)
  int id = blockIdx.x;
  int xcd = id & 7, s0i = id >> 3;
  int mg = xcd % (MT / XM), ng = xcd / (MT / XM);
  int sm = s0i % XM, sn = s0i / XM;
  int m0 = (mg * XM + sm) * TM, n0 = (ng * XN + sn) * TN;

  int srow = w * 16 + (lane >> 2);
  int sch = (lane & 3) ^ ((lane >> 3) & 3);
  const u16* Ag = A + (size_t)(m0 + srow) * K + sch * 8;
  const u16* Bg = Bt + (size_t)(n0 + srow) * K + sch * 8;

  int swl = (quad ^ ((l16 >> 1) & 3)) << 3;

  f32x4 acc[NI][NJ] = {};

#define GLD_STEP(c, kk)                                                          \
  {                                                                              \
    for (int p = 0; p < TM / 64; ++p)                                            \
      gld16(Ag + (size_t)p * 64 * K + (kk), smem + (c) * (AE + BE) + w * 512 + p * 2048); \
    for (int p = 0; p < TN / 64; ++p)                                            \
      gld16(Bg + (size_t)p * 64 * K + (kk), smem + (c) * (AE + BE) + AE + w * 512 + p * 2048); \
  }

  GLD_STEP(0, 0);
  int NS = K / 32;
  for (int s = 0; s < NS; ++s) {
    int cur = s & 1;
    __syncthreads();  // drains step-s loads (issued one compute-phase ago)
    if (s + 1 < NS) GLD_STEP(1 - cur, (s + 1) * 32);
    const __bf16* Asub = smem + cur * (AE + BE);
    const __bf16* Bsub = Asub + AE;
    bf16x8 af[NI], bfr[NJ];
    for (int i = 0; i < NI; ++i)
      af[i] = *(const bf16x8*)(Asub + (wr * (TM / 2) + i * 16 + l16) * 32 + swl);
    for (int j = 0; j < NJ; ++j)
      bfr[j] = *(const bf16x8*)(Bsub + (wc * (TN / 2) + j * 16 + l16) * 32 + swl);
    for (int i = 0; i < NI; ++i)
      for (int j = 0; j < NJ; ++j)
        acc[i][j] = __builtin_amdgcn_mfma_f32_16x16x32_bf16(af[i], bfr[j], acc[i][j], 0, 0, 0);
  }
#undef GLD_STEP

  if (MODE == 0) {
    float* O0 = (float*)O0v;
    for (int j = 0; j < NJ; ++j) {
      int n = n0 + wc * (TN / 2) + j * 16 + l16;
      float bv = bias[n];
      for (int i = 0; i < NI; ++i) {
        int mb = m0 + wr * (TM / 2) + i * 16 + quad * 4;
        for (int r = 0; r < 4; ++r)
          O0[(size_t)(mb + r) * N + n] = acc[i][j][r] + bv;
      }
    }
  } else {
    u16* O0 = (u16*)O0v;
    constexpr float QSC = 0.125f * 1.44269504f;  // softmax scale * log2(e) folded into Q
    for (int j = 0; j < NJ; ++j) {
      int n = n0 + wc * (TN / 2) + j * 16 + l16;
      int which = n >> 10, rem = n & 1023, h = rem >> 6, d = rem & 63;
      float bv = bias[n];
      for (int i = 0; i < NI; ++i) {
        int m = m0 + wr * (TM / 2) + i * 16 + quad * 4;
        int b = m >> 11, s = m & 2047;
        if (which == 2) {
          // V transposed: [b,h,d,s]; r-quad = 4 consecutive s (m) -> 8B store
          u16x4 val;
          for (int r = 0; r < 4; ++r) val[r] = f2bu(acc[i][j][r] + bv);
          *(u16x4*)(O2 + (((size_t)(b * 16 + h)) * 64 + d) * 2048 + s) = val;
        } else {
          u16* Od = which ? O1 : O0;
          float sc = which ? 1.f : QSC;
          for (int r = 0; r < 4; ++r)
            Od[(((size_t)(b * 16 + h)) * 2048 + (s + r)) * 64 + d] = f2bu((acc[i][j][r] + bv) * sc);
        }
      }
    }
  }
}

// ---------------- flash attention (R3 + in-register P via permlane swaps) -----------
// grid (B*H=32, S/128=16), 256 threads (4 waves); wave owns 32 q-rows (2 groups).
// R4 delta vs R3: the P bf16 LDS roundtrip (8 ds_write_b64 + 4 ds_read_b128 per
// iter/wave + 2 LDS-latency hops) is replaced by a pure-VALU permlane swap network.
// QK C-layout gives lane(q=l16, quad): P[q][t=16nt+4quad+r]; PV A-frag needs
// P[q=l16][t=8quad+j]. Same l16 -> redistribution is across quad bits only:
//   per half h, per word w: (G,H) = permlane16_swap(permlane32_swap(E_w, F_w))
// where E=packed nt=2h pairs, F=packed nt=2h+1 pairs. Verified element-wise.
// Ps LDS buffer deleted (48KB -> 32KB). LDS instr/iter/wave 32 -> 20.
__global__ __launch_bounds__(256, 2) void flash_attn(const u16* __restrict__ Q,
                                                     const u16* __restrict__ K,
                                                     const u16* __restrict__ Vt,
                                                     u16* __restrict__ AO) {
  constexpr int S = 2048;
  __shared__ __bf16 Ks[2][64 * 64];
  __shared__ __bf16 Vs[2][64 * 64];

  int bh = blockIdx.x, qbase = blockIdx.y * 128;
  int tid = threadIdx.x, w = tid >> 6, lane = tid & 63, quad = lane >> 4, l16 = lane & 15;

  const u16* Qh = Q + (size_t)bh * S * 64;
  const u16* Kh = K + (size_t)bh * S * 64;
  const u16* Vh = Vt + (size_t)bh * 64 * S;  // Vt[d][s]

  // two q-row groups per wave: A = w*32 + l16, B = A + 16
  int qrowA = qbase + w * 32 + l16;
  int qrowB = qrowA + 16;
  bf16x8 qf0a = *(const bf16x8*)(Qh + (size_t)qrowA * 64 + quad * 8);
  bf16x8 qf1a = *(const bf16x8*)(Qh + (size_t)qrowA * 64 + 32 + quad * 8);
  bf16x8 qf0b = *(const bf16x8*)(Qh + (size_t)qrowB * 64 + quad * 8);
  bf16x8 qf1b = *(const bf16x8*)(Qh + (size_t)qrowB * 64 + 32 + quad * 8);

  bf16x8 vone;
#pragma unroll
  for (int j = 0; j < 8; ++j) vone[j] = (__bf16)1.0f;

  int r0s = tid >> 3, b0s = tid & 7;
  int r1s = r0s + 32;
  int ko0 = r0s * 64 + ((b0s ^ (r0s & 7)) << 3);
  int ko1 = r1s * 64 + ((b0s ^ (r1s & 7)) << 3);

  bf16x8 kr0, kr1, vr0, vr1;
#define LOAD_TILE(tb)                                                   \
  {                                                                     \
    kr0 = *(const bf16x8*)(Kh + (size_t)((tb) + r0s) * 64 + b0s * 8);   \
    kr1 = *(const bf16x8*)(Kh + (size_t)((tb) + r1s) * 64 + b0s * 8);   \
    vr0 = *(const bf16x8*)(Vh + (size_t)r0s * S + (tb) + b0s * 8);      \
    vr1 = *(const bf16x8*)(Vh + (size_t)r1s * S + (tb) + b0s * 8);      \
  }
#define STORE_TILE(c)                                                   \
  {                                                                     \
    *(bf16x8*)(&Ks[c][ko0]) = kr0;                                      \
    *(bf16x8*)(&Ks[c][ko1]) = kr1;                                      \
    *(bf16x8*)(&Vs[c][ko0]) = vr0;                                      \
    *(bf16x8*)(&Vs[c][ko1]) = vr1;                                      \
  }

  LOAD_TILE(0);
  STORE_TILE(0);
  LOAD_TILE(64);
  __syncthreads();

  f32x4 oA[4] = {};
  f32x4 oB[4] = {};
  f32x4 lfA = {};
  f32x4 lfB = {};
  int xr = l16 & 7;

  for (int it = 0; it < S / 64; ++it) {
    int c = it & 1;
    if (it + 1 < S / 64) STORE_TILE(1 - c);
    if (it + 2 < S / 64) LOAD_TILE((it + 2) * 64);

    // QK^T + exp2, packed per-nt into u32 words (compiler fuses to v_cvt_pk_bf16_f32)
    u32 pwA[4][2], pwB[4][2];
#pragma unroll
    for (int nt = 0; nt < 4; ++nt) {
      const __bf16* kb = &Ks[c][(nt * 16 + l16) * 64];
      bf16x8 kf0 = *(const bf16x8*)(kb + ((quad ^ xr) << 3));
      bf16x8 kf1 = *(const bf16x8*)(kb + (((quad + 4) ^ xr) << 3));
      f32x4 ca = {0.f, 0.f, 0.f, 0.f};
      f32x4 cb = {0.f, 0.f, 0.f, 0.f};
      ca = __builtin_amdgcn_mfma_f32_16x16x32_bf16(kf0, qf0a, ca, 0, 0, 0);
      cb = __builtin_amdgcn_mfma_f32_16x16x32_bf16(kf0, qf0b, cb, 0, 0, 0);
      ca = __builtin_amdgcn_mfma_f32_16x16x32_bf16(kf1, qf1a, ca, 0, 0, 0);
      cb = __builtin_amdgcn_mfma_f32_16x16x32_bf16(kf1, qf1b, cb, 0, 0, 0);
      bf16x2 a01 = {(__bf16)__builtin_amdgcn_exp2f(ca[0]), (__bf16)__builtin_amdgcn_exp2f(ca[1])};
      bf16x2 a23 = {(__bf16)__builtin_amdgcn_exp2f(ca[2]), (__bf16)__builtin_amdgcn_exp2f(ca[3])};
      bf16x2 b01 = {(__bf16)__builtin_amdgcn_exp2f(cb[0]), (__bf16)__builtin_amdgcn_exp2f(cb[1])};
      bf16x2 b23 = {(__bf16)__builtin_amdgcn_exp2f(cb[2]), (__bf16)__builtin_amdgcn_exp2f(cb[3])};
      pwA[nt][0] = __builtin_bit_cast(u32, a01);
      pwA[nt][1] = __builtin_bit_cast(u32, a23);
      pwB[nt][0] = __builtin_bit_cast(u32, b01);
      pwB[nt][1] = __builtin_bit_cast(u32, b23);
    }

    // register-only redistribution: (E,F) -> permlane32_swap -> permlane16_swap -> (G,H)
    bf16x8 pfA[2], pfB[2];
#pragma unroll
    for (int h = 0; h < 2; ++h) {
      u32 GA[2], HA[2], GB[2], HB[2];
#pragma unroll
      for (int w2 = 0; w2 < 2; ++w2) {
        u32x2 s1a = __builtin_amdgcn_permlane32_swap(pwA[2 * h][w2], pwA[2 * h + 1][w2], false, false);
        u32x2 s2a = __builtin_amdgcn_permlane16_swap(s1a[0], s1a[1], false, false);
        GA[w2] = s2a[0];
        HA[w2] = s2a[1];
        u32x2 s1b = __builtin_amdgcn_permlane32_swap(pwB[2 * h][w2], pwB[2 * h + 1][w2], false, false);
        u32x2 s2b = __builtin_amdgcn_permlane16_swap(s1b[0], s1b[1], false, false);
        GB[w2] = s2b[0];
        HB[w2] = s2b[1];
      }
      u32x4 pa = {GA[0], GA[1], HA[0], HA[1]};
      u32x4 pb = {GB[0], GB[1], HB[0], HB[1]};
      pfA[h] = __builtin_bit_cast(bf16x8, pa);
      pfB[h] = __builtin_bit_cast(bf16x8, pb);
    }

    // l = row-sums of P via matrix pipe (B = ones); C-layout row matches o's row.
    lfA = __builtin_amdgcn_mfma_f32_16x16x32_bf16(pfA[0], vone, lfA, 0, 0, 0);
    lfA = __builtin_amdgcn_mfma_f32_16x16x32_bf16(pfA[1], vone, lfA, 0, 0, 0);
    lfB = __builtin_amdgcn_mfma_f32_16x16x32_bf16(pfB[0], vone, lfB, 0, 0, 0);
    lfB = __builtin_amdgcn_mfma_f32_16x16x32_bf16(pfB[1], vone, lfB, 0, 0, 0);

#pragma unroll
    for (int dt = 0; dt < 4; ++dt) {
      const __bf16* vb = &Vs[c][(dt * 16 + l16) * 64];
      bf16x8 v0 = *(const bf16x8*)(vb + ((quad ^ xr) << 3));
      bf16x8 v1 = *(const bf16x8*)(vb + (((quad + 4) ^ xr) << 3));
      oA[dt] = __builtin_amdgcn_mfma_f32_16x16x32_bf16(pfA[0], v0, oA[dt], 0, 0, 0);
      oB[dt] = __builtin_amdgcn_mfma_f32_16x16x32_bf16(pfB[0], v0, oB[dt], 0, 0, 0);
      oA[dt] = __builtin_amdgcn_mfma_f32_16x16x32_bf16(pfA[1], v1, oA[dt], 0, 0, 0);
      oB[dt] = __builtin_amdgcn_mfma_f32_16x16x32_bf16(pfB[1], v1, oB[dt], 0, 0, 0);
    }
    __syncthreads();
  }
#undef LOAD_TILE
#undef STORE_TILE

  float linvA[4], linvB[4];
#pragma unroll
  for (int r = 0; r < 4; ++r) {
    linvA[r] = 1.f / lfA[r];
    linvB[r] = 1.f / lfB[r];
  }

  int b = bh >> 4, h = bh & 15;
  for (int dt = 0; dt < 4; ++dt)
    for (int r = 0; r < 4; ++r) {
      int sA = qbase + w * 32 + quad * 4 + r;
      int sB = sA + 16;
      int d = dt * 16 + l16;
      AO[(((size_t)b * 2048 + sA) * 16 + h) * 64 + d] = f2bu(oA[dt][r] * linvA[r]);
      AO[(((size_t)b * 2048 + sB) * 16 + h) * 64 + d] = f2bu(oB[dt][r] * linvB[r]);
    }
}

// ---------------- launch ----------------
extern "C" void kernel_launch(void* const* d_in, const int* in_sizes, int n_in,
                              void* d_out, int out_size, void* d_ws, size_t ws_size,
                              hipStream_t stream) {
  const float* x    = (const float*)d_in[0];  // [4096,1024] f32
  const float* Wqkv = (const float*)d_in[1];  // [1024,3072] f32
  const float* bqkv = (const float*)d_in[2];  // [3072] f32
  const float* Wout = (const float*)d_in[3];  // [1024,1024] f32
  const float* bout = (const float*)d_in[4];  // [1024] f32
  float* out = (float*)d_out;                 // [4096,1024] f32

  u16* ws = (u16*)d_ws;
  size_t off = 0;
  u16* Wqkv_t = ws + off; off += (size_t)3072 * 1024;
  u16* Wout_t = ws + off; off += (size_t)1024 * 1024;
  u16* xb     = ws + off; off += (size_t)4096 * 1024;  // AO aliases xb (dead after gemm1)
  u16* Qb     = ws + off; off += (size_t)32 * 2048 * 64;
  u16* Kb     = ws + off; off += (size_t)32 * 2048 * 64;
  u16* Vtb    = ws + off; off += (size_t)32 * 2048 * 64;  // written TRANSPOSED by gemm1
  u16* AO     = xb;
  // total: ~42 MB

  prep<<<dim3(3072), 256, 0, stream>>>(Wqkv, Wqkv_t, Wout, Wout_t, x, xb);
  // gemm1: 32 m-tiles x 24 n-tiles (TM=TN=128); XCD region 8m x 12n (A 2MB + Bt 3MB / L2)
  gemm_bt<1, 128, 128, 32, 24, 8, 12><<<dim3(768), 256, 0, stream>>>(
      xb, Wqkv_t, bqkv, (void*)Qb, Kb, Vtb, 4096, 3072, 1024);
  // flash: 128 q-rows per block (32/wave), grid (B*H, S/128); blockIdx.x fastest ->
  // all q-blocks of head bh land on XCD bh%8 (4 heads x 512KB K+V = 2MB per L2)
  flash_attn<<<dim3(32, 16), 256, 0, stream>>>(Qb, Kb, Vtb, AO);
  // gemm2: 32 m-tiles x 16 n-tiles (TM=128, TN=64); XCD region 8m x 8n (A 2MB + Bt 1MB / L2)
  gemm_bt<0, 128, 64, 32, 16, 8, 8><<<dim3(512), 256, 0, stream>>>(
      AO, Wout_t, bout, (void*)out, nullptr, nullptr, 4096, 1024, 1024);
}